// Round 1
// baseline (149.631 us; speedup 1.0000x reference)
//
#include <hip/hip_runtime.h>
#include <stdint.h>

typedef __attribute__((ext_vector_type(8))) __bf16 bf16x8;
typedef __attribute__((ext_vector_type(4))) float f32x4;

#define MFMA16(a, b, c) __builtin_amdgcn_mfma_f32_16x16x32_bf16((a), (b), (c), 0, 0, 0)

__device__ __forceinline__ uint16_t f2b(float f) {
    union { float f; uint32_t u; } v; v.f = f;
    uint32_t u = v.u;
    return (uint16_t)((u + 0x7FFFu + ((u >> 16) & 1u)) >> 16);
}

__device__ __forceinline__ bf16x8 ldb8(const uint16_t* p) {
    return *(const bf16x8*)p;
}

// ---------------------------------------------------------------------------
// Kernel 0: pack weights to bf16.  Wall[320][256] = [Wq;Wk;Wv], ball[320],
// Wobf[256][512].
// ---------------------------------------------------------------------------
__global__ void pack_kernel(const float* __restrict__ Wq, const float* __restrict__ Wk,
                            const float* __restrict__ Wv, const float* __restrict__ bq,
                            const float* __restrict__ bk, const float* __restrict__ bv,
                            const float* __restrict__ Wo,
                            uint16_t* __restrict__ Wall, uint16_t* __restrict__ Wobf,
                            float* __restrict__ ball) {
    int i = blockIdx.x * blockDim.x + threadIdx.x;
    int stride = gridDim.x * blockDim.x;
    for (int idx = i; idx < 320 * 256; idx += stride) {
        int r = idx >> 8, c = idx & 255;
        float v = (r < 32) ? Wq[r * 256 + c]
                 : (r < 64) ? Wk[(r - 32) * 256 + c]
                            : Wv[(r - 64) * 256 + c];
        Wall[idx] = f2b(v);
    }
    for (int idx = i; idx < 256 * 512; idx += stride) Wobf[idx] = f2b(Wo[idx]);
    for (int idx = i; idx < 320; idx += stride)
        ball[idx] = (idx < 32) ? bq[idx] : (idx < 64) ? bk[idx - 32] : bv[idx - 64];
}

// ---------------------------------------------------------------------------
// Kernel 1: QKV projection.
// grid 256 = b(4) x ntile(64).  Emits qt[b][n][32], kt[b][n][32] (transposed,
// k-contiguous) and v[b][c][n] (c-major), all bf16.
// ---------------------------------------------------------------------------
__global__ __launch_bounds__(256) void qkv_kernel(
    const float* __restrict__ x, const uint16_t* __restrict__ Wall,
    const float* __restrict__ ball, uint16_t* __restrict__ qtg,
    uint16_t* __restrict__ ktg, uint16_t* __restrict__ vg) {
    __shared__ uint16_t xt[64][264];   // [n_local][c], pad 264 (528B stride, 16B aligned)

    const int b = blockIdx.x >> 6;
    const int n0 = (blockIdx.x & 63) * 64;
    const int t = threadIdx.x;
    const float* xb = x + (size_t)b * 256 * 4096;

    // stage x tile transposed -> bf16
    {
        const int nPart = t & 15, cIdx = t >> 4;
#pragma unroll
        for (int rep = 0; rep < 16; rep++) {
            int c = rep * 16 + cIdx;
            float4 f = *(const float4*)(xb + (size_t)c * 4096 + n0 + nPart * 4);
            xt[nPart * 4 + 0][c] = f2b(f.x);
            xt[nPart * 4 + 1][c] = f2b(f.y);
            xt[nPart * 4 + 2][c] = f2b(f.z);
            xt[nPart * 4 + 3][c] = f2b(f.w);
        }
    }
    __syncthreads();

    const int w = t >> 6, lane = t & 63, l15 = lane & 15, g = lane >> 4;

    // --- qk: D[n(64), o(64)], wave w owns m-tile w (16 n-rows) ---
    f32x4 accqk[4] = {};
#pragma unroll
    for (int ks = 0; ks < 8; ks++) {
        bf16x8 af = ldb8(&xt[w * 16 + l15][ks * 32 + g * 8]);
#pragma unroll
        for (int ot = 0; ot < 4; ot++) {
            bf16x8 bfr = ldb8(Wall + (ot * 16 + l15) * 256 + ks * 32 + g * 8);
            accqk[ot] = MFMA16(af, bfr, accqk[ot]);
        }
    }
#pragma unroll
    for (int ot = 0; ot < 4; ot++) {
        int o = ot * 16 + l15;
        float bias = ball[o];
#pragma unroll
        for (int r = 0; r < 4; r++) {
            int n = n0 + w * 16 + g * 4 + r;
            float v = accqk[ot][r] + bias;
            if (ot < 2) qtg[((size_t)b * 4096 + n) * 32 + o] = f2b(v);
            else        ktg[((size_t)b * 4096 + n) * 32 + (o - 32)] = f2b(v);
        }
    }

    // --- v: D[o(256), n(64)], wave w owns o-tiles 4w..4w+3 ---
    f32x4 accv[4][4] = {};
#pragma unroll
    for (int ks = 0; ks < 8; ks++) {
        bf16x8 av[4], bv4[4];
#pragma unroll
        for (int mt = 0; mt < 4; mt++)
            av[mt] = ldb8(Wall + (64 + (w * 4 + mt) * 16 + l15) * 256 + ks * 32 + g * 8);
#pragma unroll
        for (int nt = 0; nt < 4; nt++)
            bv4[nt] = ldb8(&xt[nt * 16 + l15][ks * 32 + g * 8]);
#pragma unroll
        for (int mt = 0; mt < 4; mt++)
#pragma unroll
            for (int nt = 0; nt < 4; nt++)
                accv[mt][nt] = MFMA16(av[mt], bv4[nt], accv[mt][nt]);
    }
#pragma unroll
    for (int mt = 0; mt < 4; mt++) {
#pragma unroll
        for (int r = 0; r < 4; r++) {
            int o = (w * 4 + mt) * 16 + g * 4 + r;
            float bias = ball[64 + o];
#pragma unroll
            for (int nt = 0; nt < 4; nt++) {
                int n = n0 + nt * 16 + l15;
                vg[((size_t)b * 256 + o) * 4096 + n] = f2b(accv[mt][nt][r] + bias);
            }
        }
    }
}

// ---------------------------------------------------------------------------
// Kernel 2: flash attention (max-free online softmax; logits bounded ~|15|).
// grid 256 = b(4) x mtile(64).  4 waves; wave w: softmax rows 16w..16w+15,
// PV c-slice [64w, 64w+64).  Writes og[b][m][256] = out^T, bf16.
// ---------------------------------------------------------------------------
__global__ __launch_bounds__(256) void attn_kernel(
    const uint16_t* __restrict__ qtg, const uint16_t* __restrict__ ktg,
    const uint16_t* __restrict__ vg, uint16_t* __restrict__ og) {
    __shared__ uint16_t qts[64][40];    // [m][c] pad 40 (80B stride)
    __shared__ uint16_t kts[64][40];    // [n][c]
    __shared__ uint16_t vts[256][72];   // [c][n] pad 72 (144B stride)
    __shared__ uint16_t pts[64][72];    // [m][n] bf16 P
    __shared__ float ls[64];            // row sums

    const int b = blockIdx.x >> 6;
    const int m0 = (blockIdx.x & 63) * 64;
    const int t = threadIdx.x, w = t >> 6, lane = t & 63, l15 = lane & 15, g = lane >> 4;

    const uint16_t* qb = qtg + (size_t)b * 4096 * 32;
    const uint16_t* kb = ktg + (size_t)b * 4096 * 32;
    const uint16_t* vb = vg + (size_t)b * 256 * 4096;

    // stage Q tile
    {
        int row = t >> 2, part = t & 3;
        *(uint4*)&qts[row][part * 8] = *(const uint4*)(qb + (size_t)(m0 + row) * 32 + part * 8);
    }
    __syncthreads();
    const bf16x8 qf = ldb8(&qts[w * 16 + l15][g * 8]);   // A-frag: wave's 16 rows, K=32

    f32x4 acc[4][4] = {};      // [m-tile][c-tile] of O[64, 64w..]
    float lpart[4] = {0.f, 0.f, 0.f, 0.f};

    for (int ch = 0; ch < 64; ch++) {
        const int n0 = ch * 64;
        __syncthreads();   // prev PV done before overwriting kts/vts/pts
        {
            int row = t >> 2, part = t & 3;
            *(uint4*)&kts[row][part * 8] =
                *(const uint4*)(kb + (size_t)(n0 + row) * 32 + part * 8);
        }
#pragma unroll
        for (int i = 0; i < 8; i++) {
            int idx = t + i * 256;
            int c = idx >> 3, p = idx & 7;
            *(uint4*)&vts[c][p * 8] = *(const uint4*)(vb + (size_t)c * 4096 + n0 + p * 8);
        }
        __syncthreads();

        // S phase: wave w computes S[16, 64] for its rows, exp, write P
        float pvv[4][4];
#pragma unroll
        for (int nt = 0; nt < 4; nt++) {
            bf16x8 kf = ldb8(&kts[nt * 16 + l15][g * 8]);
            f32x4 zero = {};
            f32x4 s = MFMA16(qf, kf, zero);
#pragma unroll
            for (int r = 0; r < 4; r++) pvv[nt][r] = __expf(s[r]);
        }
#pragma unroll
        for (int r = 0; r < 4; r++)
            lpart[r] += pvv[0][r] + pvv[1][r] + pvv[2][r] + pvv[3][r];
#pragma unroll
        for (int nt = 0; nt < 4; nt++)
#pragma unroll
            for (int r = 0; r < 4; r++)
                pts[w * 16 + g * 4 + r][nt * 16 + l15] = f2b(pvv[nt][r]);
        __syncthreads();

        // PV phase: O[all 64 m, wave's 64 c] += P[64,64] * V[64,64c]
#pragma unroll
        for (int ks = 0; ks < 2; ks++) {
            bf16x8 pa[4], vbf[4];
#pragma unroll
            for (int mt = 0; mt < 4; mt++)
                pa[mt] = ldb8(&pts[mt * 16 + l15][ks * 32 + g * 8]);
#pragma unroll
            for (int ct = 0; ct < 4; ct++)
                vbf[ct] = ldb8(&vts[w * 64 + ct * 16 + l15][ks * 32 + g * 8]);
#pragma unroll
            for (int mt = 0; mt < 4; mt++)
#pragma unroll
                for (int ct = 0; ct < 4; ct++)
                    acc[mt][ct] = MFMA16(pa[mt], vbf[ct], acc[mt][ct]);
        }
    }

    // reduce row sums across the 16-lane col groups, share via LDS
#pragma unroll
    for (int r = 0; r < 4; r++) {
        float v = lpart[r];
        v += __shfl_xor(v, 1);
        v += __shfl_xor(v, 2);
        v += __shfl_xor(v, 4);
        v += __shfl_xor(v, 8);
        if (l15 == 0) ls[w * 16 + g * 4 + r] = v;
    }
    __syncthreads();

#pragma unroll
    for (int mt = 0; mt < 4; mt++) {
        float rinv[4];
#pragma unroll
        for (int r = 0; r < 4; r++) rinv[r] = 1.0f / ls[mt * 16 + g * 4 + r];
#pragma unroll
        for (int ct = 0; ct < 4; ct++)
#pragma unroll
            for (int r = 0; r < 4; r++) {
                size_t idx = ((size_t)b * 4096 + m0 + mt * 16 + g * 4 + r) * 256
                           + w * 64 + ct * 16 + l15;
                og[idx] = f2b(acc[mt][ct][r] * rinv[r]);
            }
    }
}

// ---------------------------------------------------------------------------
// Kernel 3: y = Wo[:, :256] @ out + Wo[:, 256:] @ x + bo.
// grid 256 = b(4) x mtile(64).  D[o(256), m(64)]; A = Wobf rows (global),
// B: out-part direct from og (already k-contiguous), x-part via LDS transpose.
// ---------------------------------------------------------------------------
__global__ __launch_bounds__(256) void out_kernel(
    const float* __restrict__ x, const uint16_t* __restrict__ og,
    const uint16_t* __restrict__ Wobf, const float* __restrict__ bo,
    float* __restrict__ y) {
    __shared__ uint16_t xt[64][264];

    const int b = blockIdx.x >> 6;
    const int m0 = (blockIdx.x & 63) * 64;
    const int t = threadIdx.x;
    const float* xb = x + (size_t)b * 256 * 4096;

    {
        const int nPart = t & 15, cIdx = t >> 4;
#pragma unroll
        for (int rep = 0; rep < 16; rep++) {
            int c = rep * 16 + cIdx;
            float4 f = *(const float4*)(xb + (size_t)c * 4096 + m0 + nPart * 4);
            xt[nPart * 4 + 0][c] = f2b(f.x);
            xt[nPart * 4 + 1][c] = f2b(f.y);
            xt[nPart * 4 + 2][c] = f2b(f.z);
            xt[nPart * 4 + 3][c] = f2b(f.w);
        }
    }
    __syncthreads();

    const int w = t >> 6, lane = t & 63, l15 = lane & 15, g = lane >> 4;
    const uint16_t* ob = og + ((size_t)b * 4096 + m0) * 256;

    f32x4 acc[4][4] = {};   // [o-tile][m-tile]
    // out-part: k = 0..255
#pragma unroll
    for (int ks = 0; ks < 8; ks++) {
        bf16x8 af[4], bfr[4];
#pragma unroll
        for (int mt = 0; mt < 4; mt++)
            af[mt] = ldb8(Wobf + ((w * 4 + mt) * 16 + l15) * 512 + ks * 32 + g * 8);
#pragma unroll
        for (int nt = 0; nt < 4; nt++)
            bfr[nt] = ldb8(ob + (size_t)(nt * 16 + l15) * 256 + ks * 32 + g * 8);
#pragma unroll
        for (int mt = 0; mt < 4; mt++)
#pragma unroll
            for (int nt = 0; nt < 4; nt++)
                acc[mt][nt] = MFMA16(af[mt], bfr[nt], acc[mt][nt]);
    }
    // x-part: k = 256..511
#pragma unroll
    for (int ks = 0; ks < 8; ks++) {
        bf16x8 af[4], bfr[4];
#pragma unroll
        for (int mt = 0; mt < 4; mt++)
            af[mt] = ldb8(Wobf + ((w * 4 + mt) * 16 + l15) * 512 + 256 + ks * 32 + g * 8);
#pragma unroll
        for (int nt = 0; nt < 4; nt++)
            bfr[nt] = ldb8(&xt[nt * 16 + l15][ks * 32 + g * 8]);
#pragma unroll
        for (int mt = 0; mt < 4; mt++)
#pragma unroll
            for (int nt = 0; nt < 4; nt++)
                acc[mt][nt] = MFMA16(af[mt], bfr[nt], acc[mt][nt]);
    }

#pragma unroll
    for (int mt = 0; mt < 4; mt++)
#pragma unroll
        for (int r = 0; r < 4; r++) {
            int o = (w * 4 + mt) * 16 + g * 4 + r;
            float bias = bo[o];
#pragma unroll
            for (int nt = 0; nt < 4; nt++) {
                int m = m0 + nt * 16 + l15;
                y[((size_t)b * 256 + o) * 4096 + m] = acc[mt][nt][r] + bias;
            }
        }
}

// ---------------------------------------------------------------------------
extern "C" void kernel_launch(void* const* d_in, const int* in_sizes, int n_in,
                              void* d_out, int out_size, void* d_ws, size_t ws_size,
                              hipStream_t stream) {
    const float* x  = (const float*)d_in[0];
    const float* Wq = (const float*)d_in[1];
    const float* bq = (const float*)d_in[2];
    const float* Wk = (const float*)d_in[3];
    const float* bk = (const float*)d_in[4];
    const float* Wv = (const float*)d_in[5];
    const float* bv = (const float*)d_in[6];
    const float* Wo = (const float*)d_in[7];
    const float* bo = (const float*)d_in[8];
    float* y = (float*)d_out;

    char* ws = (char*)d_ws;
    uint16_t* Wall = (uint16_t*)(ws + 0);          // 163840 B
    uint16_t* Wobf = (uint16_t*)(ws + 163840);     // 262144 B
    float*    ball = (float*)(ws + 425984);        // 1280 B
    uint16_t* qtg  = (uint16_t*)(ws + 427520);     // 1 MiB
    uint16_t* ktg  = (uint16_t*)(ws + 1476096);    // 1 MiB
    uint16_t* vgw  = (uint16_t*)(ws + 2524672);    // 8 MiB
    uint16_t* ogw  = (uint16_t*)(ws + 10913280);   // 8 MiB  (end 19301888)

    pack_kernel<<<256, 256, 0, stream>>>(Wq, Wk, Wv, bq, bk, bv, Wo, Wall, Wobf, ball);
    qkv_kernel<<<256, 256, 0, stream>>>(x, Wall, ball, qtg, ktg, vgw);
    attn_kernel<<<256, 256, 0, stream>>>(qtg, ktg, vgw, ogw);
    out_kernel<<<256, 256, 0, stream>>>(x, ogw, Wobf, bo, y);
}